// Round 1
// baseline (4530.101 us; speedup 1.0000x reference)
//
#include <hip/hip_runtime.h>
#include <math.h>

#define N_NODES 100000
#define N_EDGES 1600000
#define F_IN 92
#define E_IN 50
#define D 64
#define N_LAYERS 3
#define N_GRAPHS 512
#define BN_EPS 1e-5f

__device__ __forceinline__ float silu_f(float x) {
    return x / (1.0f + __expf(-x));
}

// h = silu(x @ pre_w + pre_b)   [N_NODES, F_IN] @ [F_IN, D]
__global__ __launch_bounds__(256) void pre_fc_kernel(
    const float* __restrict__ x, const float* __restrict__ w,
    const float* __restrict__ b, float* __restrict__ h) {
    __shared__ float xs[4][F_IN];
    int d = threadIdx.x;        // 0..63
    int yy = threadIdx.y;       // 0..3
    int node = blockIdx.x * 4 + yy;
    if (node < N_NODES) {
        const float* xrow = x + (long)node * F_IN;
        for (int i = d; i < F_IN; i += 64) xs[yy][i] = xrow[i];
    }
    __syncthreads();
    if (node >= N_NODES) return;
    float acc = b[d];
#pragma unroll 4
    for (int i = 0; i < F_IN; ++i) acc = fmaf(xs[yy][i], w[i * D + d], acc);
    h[(long)node * D + d] = silu_f(acc);
}

// k = h@Wk+bk, q = h@Wq+bq, v = h@Wv+bv  (per node, all three fused)
__global__ __launch_bounds__(256) void node_proj_kernel(
    const float* __restrict__ h,
    const float* __restrict__ Wk, const float* __restrict__ bk,
    const float* __restrict__ Wq, const float* __restrict__ bq,
    const float* __restrict__ Wv, const float* __restrict__ bv,
    float* __restrict__ ko, float* __restrict__ qo, float* __restrict__ vo) {
    __shared__ float hs[4][D];
    int d = threadIdx.x, yy = threadIdx.y;
    int node = blockIdx.x * 4 + yy;
    if (node < N_NODES) hs[yy][d] = h[(long)node * D + d];
    __syncthreads();
    if (node >= N_NODES) return;
    float ak = bk[d], aq = bq[d], av = bv[d];
#pragma unroll 8
    for (int i = 0; i < D; ++i) {
        float hv = hs[yy][i];
        ak = fmaf(hv, Wk[i * D + d], ak);
        aq = fmaf(hv, Wq[i * D + d], aq);
        av = fmaf(hv, Wv[i * D + d], av);
    }
    long off = (long)node * D + d;
    ko[off] = ak; qo[off] = aq; vo[off] = av;
}

// Fused: e = edge_attr@We ; gate = silu(k[dst]+q[src]+2e) ; msg = gate*(v[src]+e)
// atomicAdd into agg[dst]
__global__ __launch_bounds__(256) void edge_kernel(
    const float* __restrict__ ea, const int* __restrict__ srcIdx,
    const int* __restrict__ dstIdx, const float* __restrict__ We,
    const float* __restrict__ kb, const float* __restrict__ qb,
    const float* __restrict__ vb, float* __restrict__ agg) {
    __shared__ float eas[4][E_IN];
    int d = threadIdx.x, yy = threadIdx.y;
    int e = blockIdx.x * 4 + yy;
    if (e < N_EDGES) {
        const float* erow = ea + (long)e * E_IN;
        if (d < E_IN) eas[yy][d] = erow[d];
    }
    __syncthreads();
    if (e >= N_EDGES) return;
    int s = srcIdx[e];
    int t = dstIdx[e];
    float ed = 0.f;
#pragma unroll 5
    for (int i = 0; i < E_IN; ++i) ed = fmaf(eas[yy][i], We[i * D + d], ed);
    float kv = kb[(long)t * D + d];
    float qv = qb[(long)s * D + d];
    float vv = vb[(long)s * D + d];
    float gate = silu_f(kv + qv + 2.0f * ed);
    float msg = gate * (vv + ed);
    atomicAdd(&agg[(long)t * D + d], msg);
}

// hnew = agg + h@Wskip + conv_bias
__global__ __launch_bounds__(256) void combine_kernel(
    const float* __restrict__ agg, const float* __restrict__ h,
    const float* __restrict__ Wskip, const float* __restrict__ bias,
    float* __restrict__ hnew) {
    __shared__ float hs[4][D];
    int d = threadIdx.x, yy = threadIdx.y;
    int node = blockIdx.x * 4 + yy;
    if (node < N_NODES) hs[yy][d] = h[(long)node * D + d];
    __syncthreads();
    if (node >= N_NODES) return;
    float acc = bias[d];
#pragma unroll 8
    for (int i = 0; i < D; ++i) acc = fmaf(hs[yy][i], Wskip[i * D + d], acc);
    long off = (long)node * D + d;
    hnew[off] = agg[off] + acc;
}

// per-column sum & sumsq into stats[0:64], stats[64:128]
__global__ __launch_bounds__(256) void bn_stats_kernel(
    const float* __restrict__ hnew, float* __restrict__ stats) {
    int d = threadIdx.x, yy = threadIdx.y;
    float s = 0.f, s2 = 0.f;
    for (int n = blockIdx.x * 4 + yy; n < N_NODES; n += gridDim.x * 4) {
        float v = hnew[(long)n * D + d];
        s += v;
        s2 = fmaf(v, v, s2);
    }
    __shared__ float ls[4][D], ls2[4][D];
    ls[yy][d] = s; ls2[yy][d] = s2;
    __syncthreads();
    if (yy == 0) {
        float ts = ls[0][d] + ls[1][d] + ls[2][d] + ls[3][d];
        float ts2 = ls2[0][d] + ls2[1][d] + ls2[2][d] + ls2[3][d];
        atomicAdd(&stats[d], ts);
        atomicAdd(&stats[D + d], ts2);
    }
}

// h = (hnew - mean) * rsqrt(var+eps) * gamma + beta  (biased var)
__global__ __launch_bounds__(256) void bn_apply_kernel(
    const float* __restrict__ hnew, const float* __restrict__ stats,
    const float* __restrict__ gamma, const float* __restrict__ beta,
    float* __restrict__ h) {
    long idx = (long)blockIdx.x * 256 + threadIdx.x;
    if (idx >= (long)N_NODES * D) return;
    int d = (int)(idx & (D - 1));
    const float invN = 1.0f / (float)N_NODES;
    float mean = stats[d] * invN;
    float var = stats[D + d] * invN - mean * mean;
    float sc = rsqrtf(var + BN_EPS) * gamma[d];
    h[idx] = (hnew[idx] - mean) * sc + beta[d];
}

// batch_idx sorted -> start[g] = first node of graph g; start[N_GRAPHS] = N_NODES
__global__ __launch_bounds__(256) void graph_bounds_kernel(
    const int* __restrict__ batch, int* __restrict__ start) {
    int n = blockIdx.x * 256 + threadIdx.x;
    if (n >= N_NODES) return;
    int b = batch[n];
    if (n == 0) {
        for (int g = 0; g <= b; ++g) start[g] = 0;
    } else {
        int p = batch[n - 1];
        for (int g = p + 1; g <= b; ++g) start[g] = n;
    }
    if (n == N_NODES - 1) {
        for (int g = b + 1; g <= N_GRAPHS; ++g) start[g] = N_NODES;
    }
}

// global mean pool + post FC + silu + output head (one block per graph)
__global__ __launch_bounds__(256) void pool_head_kernel(
    const float* __restrict__ h, const int* __restrict__ start,
    const float* __restrict__ pw, const float* __restrict__ pb,
    const float* __restrict__ ow, const float* __restrict__ ob,
    float* __restrict__ out) {
    int g = blockIdx.x;
    int d = threadIdx.x, yy = threadIdx.y;
    int lo = start[g], hi = start[g + 1];
    float s = 0.f;
    for (int n = lo + yy; n < hi; n += 4) s += h[(long)n * D + d];
    __shared__ float ls[4][D];
    ls[yy][d] = s;
    __syncthreads();
    __shared__ float grow[D];
    if (yy == 0) {
        float cnt = (float)(hi - lo);
        float tot = ls[0][d] + ls[1][d] + ls[2][d] + ls[3][d];
        grow[d] = tot / fmaxf(cnt, 1.0f);
    }
    __syncthreads();
    if (yy != 0) return;
    float acc = pb[d];
#pragma unroll 8
    for (int i = 0; i < D; ++i) acc = fmaf(grow[i], pw[i * D + d], acc);
    float sv = silu_f(acc) * ow[d];
    // wave-64 reduction
    for (int off = 32; off > 0; off >>= 1) sv += __shfl_down(sv, off);
    if (d == 0) out[g] = sv + ob[0];
}

extern "C" void kernel_launch(void* const* d_in, const int* in_sizes, int n_in,
                              void* d_out, int out_size, void* d_ws, size_t ws_size,
                              hipStream_t stream) {
    const float* x        = (const float*)d_in[0];
    const int*   ei       = (const int*)d_in[1];
    const float* ea       = (const float*)d_in[2];
    const int*   batch    = (const int*)d_in[3];
    const float* pre_w    = (const float*)d_in[4];
    const float* pre_b    = (const float*)d_in[5];
    const float* Wk       = (const float*)d_in[6];
    const float* bk       = (const float*)d_in[7];
    const float* Wq       = (const float*)d_in[8];
    const float* bq       = (const float*)d_in[9];
    const float* Wv       = (const float*)d_in[10];
    const float* bv       = (const float*)d_in[11];
    const float* We       = (const float*)d_in[12];
    const float* Wskip    = (const float*)d_in[13];
    const float* conv_bias= (const float*)d_in[14];
    const float* bn_gamma = (const float*)d_in[15];
    const float* bn_beta  = (const float*)d_in[16];
    const float* post_w   = (const float*)d_in[17];
    const float* post_b   = (const float*)d_in[18];
    const float* out_w    = (const float*)d_in[19];
    const float* out_b    = (const float*)d_in[20];

    float* ws = (float*)d_ws;
    const size_t NH = (size_t)N_NODES * D;
    float* h     = ws;
    float* kb    = ws + NH;        // also reused as hnew
    float* qb    = ws + 2 * NH;
    float* vb    = ws + 3 * NH;
    float* agg   = ws + 4 * NH;
    float* stats = ws + 5 * NH;            // 2*D floats
    int*   start = (int*)(ws + 5 * NH + 2 * D);  // N_GRAPHS+1 ints

    const int* srcIdx = ei;
    const int* dstIdx = ei + N_EDGES;

    dim3 blk(64, 4);
    pre_fc_kernel<<<(N_NODES + 3) / 4, blk, 0, stream>>>(x, pre_w, pre_b, h);

    for (int l = 0; l < N_LAYERS; ++l) {
        node_proj_kernel<<<(N_NODES + 3) / 4, blk, 0, stream>>>(
            h, Wk + l * D * D, bk + l * D, Wq + l * D * D, bq + l * D,
            Wv + l * D * D, bv + l * D, kb, qb, vb);
        hipMemsetAsync(agg, 0, NH * sizeof(float), stream);
        edge_kernel<<<(N_EDGES + 3) / 4, blk, 0, stream>>>(
            ea, srcIdx, dstIdx, We + l * E_IN * D, kb, qb, vb, agg);
        combine_kernel<<<(N_NODES + 3) / 4, blk, 0, stream>>>(
            agg, h, Wskip + l * D * D, conv_bias + l * D, kb);  // hnew -> kb
        hipMemsetAsync(stats, 0, 2 * D * sizeof(float), stream);
        bn_stats_kernel<<<256, blk, 0, stream>>>(kb, stats);
        bn_apply_kernel<<<(int)((NH + 255) / 256), 256, 0, stream>>>(
            kb, stats, bn_gamma + l * D, bn_beta + l * D, h);
    }

    graph_bounds_kernel<<<(N_NODES + 255) / 256, 256, 0, stream>>>(batch, start);
    pool_head_kernel<<<N_GRAPHS, blk, 0, stream>>>(
        h, start, post_w, post_b, out_w, out_b, (float*)d_out);
}